// Round 12
// baseline (676.282 us; speedup 1.0000x reference)
//
#include <hip/hip_runtime.h>
#include <hip/hip_bf16.h>
#include <math.h>

#define H 128
#define EMBD 128
#define VOCAB 50000

typedef __attribute__((ext_vector_type(8))) short bf16x8;
typedef __attribute__((ext_vector_type(4))) float f32x4;

constexpr int BLOCK = 128;   // fp32 path: one thread per hidden dim
constexpr int NTOT = 131071 + 4095 + 4095;   // 139261

// fp32-path packed weights: g_pack[k][j][8]
__device__ float g_pack[128 * 128 * 8];
// MFMA packed weights, transposed [col][k'], k' bands = [hi(384) | hi-dup(384) | lo(384)]
__device__ unsigned short g_Biou[384 * 1152];
__device__ unsigned short g_Bf[256 * 1152];
__device__ unsigned short g_Bleaf[384 * 384];
// emb pre-split to bf16: row f = [hi(128) | lo(128)]
__device__ unsigned short g_embhl[VOCAB * 256];

// ---- shared-B schedule tables [MODE][bkt] ----
constexpr int SB_NBT[3] = {12, 8, 4};
constexpr int SB_KOFF[3][12] = {
    {0, 64, 128, 192, 256, 320, 768, 832, 896, 960, 1024, 1088},  // F
    {0, 64, 128, 192, 768, 832, 896, 960},                        // IOU
    {0, 64, 256, 320}                                             // leaf
};
constexpr int SB_NPL[3][12] = {
    {2, 2, 2, 2, 2, 2, 1, 1, 1, 1, 1, 1},
    {2, 2, 4, 4, 1, 1, 2, 2},
    {2, 2, 1, 1}
};
constexpr int SB_SEL[3][12][4] = {
    {{0,0},{0,0},{1,2},{1,2},{1,2},{1,2},{0},{0},{1},{1},{1},{1}},
    {{0,0},{0,0},{1,1,2,2},{1,1,2,2},{0},{0},{1,1},{1,1}},
    {{0,0},{0,0},{0},{0}}
};
constexpr int SB_OFF[3][12][4] = {
    {{0,128},{64,192},{0,0},{64,64},{128,128},{192,192},{0},{64},{0},{64},{128},{192}},
    {{0,128},{64,192},{0,128,0,128},{64,192,64,192},{0},{64},{0,128},{64,192}},
    {{0,128},{64,192},{0},{64}}
};

struct TreeSeg { int start, cnt, hcOff, N; };

__device__ __forceinline__ float fast_sig(float x)  { return 1.0f / (1.0f + __expf(-x)); }
__device__ __forceinline__ float fast_tanh(float x) { return 1.0f - 2.0f / (__expf(2.0f * x) + 1.0f); }
__device__ __forceinline__ unsigned short f2bf(float f) {
    unsigned int u = __float_as_uint(f);
    return (unsigned short)((u + 0x7FFFu + ((u >> 16) & 1u)) >> 16);
}
__device__ __forceinline__ float bf2f(unsigned short h) {
    return __uint_as_float(((unsigned int)h) << 16);
}
__device__ __forceinline__ unsigned short bf_split(float v, bool lo) {
    unsigned short hi = f2bf(v);
    return lo ? f2bf(v - bf2f(hi)) : hi;
}

// ---------------- pack kernels ----------------
__global__ __launch_bounds__(128)
void pack_kernel(const float* __restrict__ Wiou, const float* __restrict__ Wf,
                 const float* __restrict__ Uiou, const float* __restrict__ Uf)
{
    const int k = blockIdx.x;
    const int j = threadIdx.x;
    float4 a, b;
    a.x = Wiou[k * 384 + j];
    a.y = Wiou[k * 384 + 128 + j];
    a.z = Wiou[k * 384 + 256 + j];
    a.w = Wf[k * 128 + j];
    b.x = Uiou[k * 384 + j];
    b.y = Uiou[k * 384 + 128 + j];
    b.z = Uiou[k * 384 + 256 + j];
    b.w = Uf[k * 128 + j];
    float4* o = reinterpret_cast<float4*>(g_pack + ((size_t)k * 128 + j) * 8);
    o[0] = a;
    o[1] = b;
}

__global__ __launch_bounds__(256)
void pack_B(const float* __restrict__ Wiou, const float* __restrict__ Uiou,
            const float* __restrict__ Wf, const float* __restrict__ Uf)
{
    const int NB1 = 384 * 1152, NB2 = NB1 + 256 * 1152, NB3 = NB2 + 384 * 384;
    int idx = blockIdx.x * 256 + threadIdx.x;
    if (idx < NB1) {
        int c = idx / 1152, k = idx % 1152;
        int kb = k % 384; bool lo = k >= 768;
        float v = (kb < 128) ? Wiou[kb * 384 + c] : Uiou[((kb - 128) & 127) * 384 + c];
        g_Biou[c * 1152 + k] = bf_split(v, lo);
    } else if (idx < NB2) {
        int r = idx - NB1;
        int c = r / 1152, k = r % 1152;
        int kb = k % 384; bool lo = k >= 768;
        int g = c >> 7, j = c & 127;
        float v;
        if (kb < 128)      v = Wf[kb * 128 + j];
        else if (kb < 256) v = (g == 0) ? Uf[(kb - 128) * 128 + j] : 0.0f;
        else               v = (g == 1) ? Uf[(kb - 256) * 128 + j] : 0.0f;
        g_Bf[c * 1152 + k] = bf_split(v, lo);
    } else if (idx < NB3) {
        int r = idx - NB2;
        int c = r / 384, k = r % 384;
        int kb = k % 128; bool lo = k >= 256;
        g_Bleaf[c * 384 + k] = bf_split(Wiou[kb * 384 + c], lo);
    }
}

__global__ __launch_bounds__(256)
void pack_emb(const float* __restrict__ emb)
{
    int idx = blockIdx.x * 256 + threadIdx.x;
    if (idx >= VOCAB * 32) return;
    const int f = idx >> 5, k4 = idx & 31;
    float4 v = reinterpret_cast<const float4*>(emb + (size_t)f * 128)[k4];
    const float fv[4] = {v.x, v.y, v.z, v.w};
    ushort4 hi4, lo4;
    unsigned short* hp = reinterpret_cast<unsigned short*>(&hi4);
    unsigned short* lp = reinterpret_cast<unsigned short*>(&lo4);
    #pragma unroll
    for (int t = 0; t < 4; ++t) {
        unsigned short hb = f2bf(fv[t]);
        hp[t] = hb;
        lp[t] = f2bf(fv[t] - bf2f(hb));
    }
    *reinterpret_cast<ushort4*>(g_embhl + (size_t)f * 256 + k4 * 4) = hi4;
    *reinterpret_cast<ushort4*>(g_embhl + (size_t)f * 256 + 128 + k4 * 4) = lo4;
}

// ---------------- MFMA level GEMM, 64-row tiles (masked), shared-B staging ----------------
// MODE 0 = F (NCH=2), 1 = IOU (NCH=3), 2 = IOU leaf (NCH=3, K'=384)
template<int NCH, int MODE>
__global__ __launch_bounds__(512, 2)
void gemm_level(const int* __restrict__ feat0, const int* __restrict__ feat1,
                const int* __restrict__ feat2,
                const unsigned short* __restrict__ hhi, const unsigned short* __restrict__ hlo,
                unsigned short* __restrict__ whhi, unsigned short* __restrict__ whlo,
                float* __restrict__ cbuf,
                const float* __restrict__ b_iou, const float* __restrict__ b_f,
                TreeSeg s0, TreeSeg s1, TreeSeg s2, int blocks0, int blocks01)
{
    constexpr int KP   = (MODE == 2) ? 384 : 1152;
    constexpr int NBT  = SB_NBT[MODE];
    constexpr int MAXP = (MODE == 1) ? 4 : 2;
    constexpr int NB   = NCH * 2;
    __shared__ unsigned short Als[MAXP][64 * 64];
    __shared__ unsigned short Bls[NCH * 128 * 64];

    const int bid = blockIdx.x;
    TreeSeg seg; const int* feat; int batch;
    if (bid < blocks0)       { seg = s0; feat = feat0; batch = bid; }
    else if (bid < blocks01) { seg = s1; feat = feat1; batch = bid - blocks0; }
    else                     { seg = s2; feat = feat2; batch = bid - blocks01; }

    const int tid = threadIdx.x;
    const int nbase = seg.start + batch * 64;
    const int vrows = min(64, seg.cnt - batch * 64);   // valid rows in this block

    // A staging: thread -> (row, slot); clamp tail rows to a valid node
    const int arow = tid >> 3, aslot = tid & 7;
    const int agnode = nbase + min(arow, vrows - 1);
    const unsigned short* erow = g_embhl + (size_t)feat[agnode] * 256 + aslot * 8;
    const unsigned short* hrhi = erow;
    const unsigned short* hrlo = erow;
    if (MODE != 2) {
        const size_t hbase = (size_t)(seg.hcOff + 2 * agnode - seg.N - 1) * 128 + aslot * 8;
        hrhi = hhi + hbase;
        hrlo = hlo + hbase;
    }
    const int adst = arow * 64 + ((aslot ^ (arow & 7)) << 3);

    // B staging: single base + constexpr chunk offsets (low VGPR)
    const unsigned short* BT = (MODE == 0) ? g_Bf : ((MODE == 2) ? g_Bleaf : g_Biou);
    const int col0 = tid >> 3, slot = tid & 7;
    const unsigned short* bbase = BT + (size_t)col0 * KP + slot * 8;
    const int bd0 = col0 * 64 + ((slot ^ (col0 & 7)) << 3);

    auto srcPlane = [&](int bkt, int p) -> const unsigned short* {
        const int s = SB_SEL[MODE][bkt][p];
        const unsigned short* base = (s == 0) ? erow : ((s == 1) ? hrhi : hrlo);
        return base + SB_OFF[MODE][bkt][p];
    };

    f32x4 acc[2][NCH][2];
    #pragma unroll
    for (int a = 0; a < 2; ++a)
        #pragma unroll
        for (int b = 0; b < NCH; ++b)
            #pragma unroll
            for (int d = 0; d < 2; ++d) acc[a][b][d] = (f32x4){0.f, 0.f, 0.f, 0.f};

    const int lane = tid & 63;
    const int wv = tid >> 6;
    const int wm = wv >> 2, wn = wv & 3;
    const int l15 = lane & 15, l4 = lane >> 4;

    auto mfma_phase = [&](int at) {
        #pragma unroll
        for (int st = 0; st < 2; ++st) {
            const int q = st * 4 + l4;
            bf16x8 af[2];
            #pragma unroll
            for (int fm = 0; fm < 2; ++fm) {
                const int row = wm * 32 + fm * 16 + l15;
                af[fm] = *reinterpret_cast<const bf16x8*>(&Als[at][row * 64 + ((q ^ (row & 7)) << 3)]);
            }
            #pragma unroll
            for (int ch = 0; ch < NCH; ++ch) {
                #pragma unroll
                for (int fc = 0; fc < 2; ++fc) {
                    const int col = ch * 128 + wn * 32 + fc * 16 + l15;
                    const bf16x8 bfr = *reinterpret_cast<const bf16x8*>(&Bls[col * 64 + ((q ^ (col & 7)) << 3)]);
                    #pragma unroll
                    for (int fm = 0; fm < 2; ++fm)
                        acc[fm][ch][fc] = __builtin_amdgcn_mfma_f32_16x16x32_bf16(af[fm], bfr, acc[fm][ch][fc], 0, 0, 0);
                }
            }
        }
    };

    // prologue: prefetch bkt 0
    bf16x8 aR[MAXP], bR[NB];
    #pragma unroll
    for (int it = 0; it < NB; ++it)
        bR[it] = *reinterpret_cast<const bf16x8*>(bbase + (size_t)it * 64 * KP + SB_KOFF[MODE][0]);
    #pragma unroll
    for (int p = 0; p < MAXP; ++p)
        if (p < SB_NPL[MODE][0]) aR[p] = *reinterpret_cast<const bf16x8*>(srcPlane(0, p));

    #pragma unroll
    for (int bkt = 0; bkt < NBT; ++bkt) {
        #pragma unroll
        for (int it = 0; it < NB; ++it)
            *reinterpret_cast<bf16x8*>(&Bls[bd0 + it * 64 * 64]) = bR[it];
        #pragma unroll
        for (int p = 0; p < MAXP; ++p)
            if (p < SB_NPL[MODE][bkt]) *reinterpret_cast<bf16x8*>(&Als[p][adst]) = aR[p];
        if (bkt + 1 < NBT) {
            #pragma unroll
            for (int it = 0; it < NB; ++it)
                bR[it] = *reinterpret_cast<const bf16x8*>(bbase + (size_t)it * 64 * KP + SB_KOFF[MODE][bkt + 1]);
            #pragma unroll
            for (int p = 0; p < MAXP; ++p)
                if (p < SB_NPL[MODE][bkt + 1]) aR[p] = *reinterpret_cast<const bf16x8*>(srcPlane(bkt + 1, p));
        }
        __syncthreads();
        #pragma unroll
        for (int p = 0; p < MAXP; ++p)
            if (p < SB_NPL[MODE][bkt]) mfma_phase(p);
        __syncthreads();
    }

    // ---- fused epilogue (guarded stores for partial blocks) ----
    #pragma unroll
    for (int fc = 0; fc < 2; ++fc) {
        const int j = wn * 32 + fc * 16 + l15;
        float bi = 0.f, bo = 0.f, bu = 0.f, bff = 0.f;
        if (MODE == 0) { bff = b_f[j]; }
        else { bi = b_iou[j]; bo = b_iou[128 + j]; bu = b_iou[256 + j]; }
        #pragma unroll
        for (int fm = 0; fm < 2; ++fm) {
            #pragma unroll
            for (int r = 0; r < 4; ++r) {
                const int row_local = wm * 32 + fm * 16 + l4 * 4 + r;
                if (row_local >= vrows) continue;
                const int gnode = nbase + row_local;
                const size_t crow = (size_t)(seg.hcOff + gnode) * 128;
                if constexpr (MODE == 0) {
                    const size_t cbase = (size_t)(seg.hcOff + 2 * gnode - seg.N - 1) * 128;
                    const float fa = fast_sig(acc[fm][0][fc][r] + bff);
                    const float fb = fast_sig(acc[fm][1][fc][r] + bff);
                    cbuf[crow + j] = fa * cbuf[cbase + j] + fb * cbuf[cbase + 128 + j];
                } else {
                    const float iv = fast_sig(acc[fm][0][fc][r] + bi);
                    const float ov = fast_sig(acc[fm][1][fc][r] + bo);
                    const float uv = fast_tanh(acc[fm][NCH - 1][fc][r] + bu);
                    float cn = iv * uv;
                    if (MODE == 1) cn += cbuf[crow + j];
                    cbuf[crow + j] = cn;
                    const float hn = ov * fast_tanh(cn);
                    const unsigned short hi16 = f2bf(hn);
                    whhi[crow + j] = hi16;
                    whlo[crow + j] = f2bf(hn - bf2f(hi16));
                }
            }
        }
    }
}

// ---------------- fp32 path for levels 12..16 (tiny) ----------------
template<int NP, bool LEAF>
__global__ __launch_bounds__(BLOCK, 2)
void level_kernel(const float* __restrict__ emb,
                  const float* __restrict__ b_iou, const float* __restrict__ b_f,
                  const int* __restrict__ feat0, const int* __restrict__ feat1,
                  const int* __restrict__ feat2,
                  const unsigned short* __restrict__ hhi, const unsigned short* __restrict__ hlo,
                  unsigned short* __restrict__ whhi, unsigned short* __restrict__ whlo,
                  float* __restrict__ cbuf,
                  TreeSeg s0, TreeSeg s1, TreeSeg s2,
                  int blocks0, int blocks01)
{
    __shared__ float xe[NP][EMBD];
    __shared__ float ha[LEAF ? 1 : NP][EMBD];
    __shared__ float hb[LEAF ? 1 : NP][EMBD];

    const int bid = blockIdx.x;
    TreeSeg seg; const int* feat; int batch;
    if (bid < blocks0)       { seg = s0; feat = feat0; batch = bid; }
    else if (bid < blocks01) { seg = s1; feat = feat1; batch = bid - blocks0; }
    else                     { seg = s2; feat = feat2; batch = bid - blocks01; }

    const int tid = threadIdx.x;
    const int nbase = seg.start + batch * NP;
    const int nval  = min(NP, seg.start + seg.cnt - nbase);

    for (int idx = tid; idx < NP * (EMBD / 4); idx += BLOCK) {
        const int n  = idx >> 5;
        const int k4 = idx & 31;
        const int node = nbase + min(n, nval - 1);
        const int f = feat[node];
        float4 v = reinterpret_cast<const float4*>(emb + (size_t)f * EMBD)[k4];
        *reinterpret_cast<float4*>(&xe[n][k4 * 4]) = v;
        if (!LEAF) {
            const int a = 2 * node - seg.N - 1;
            const size_t ra = (size_t)(seg.hcOff + a) * H + k4 * 4;
            ushort4 h4 = *reinterpret_cast<const ushort4*>(hhi + ra);
            ushort4 l4v = *reinterpret_cast<const ushort4*>(hlo + ra);
            float4 va;
            va.x = bf2f(h4.x) + bf2f(l4v.x);
            va.y = bf2f(h4.y) + bf2f(l4v.y);
            va.z = bf2f(h4.z) + bf2f(l4v.z);
            va.w = bf2f(h4.w) + bf2f(l4v.w);
            *reinterpret_cast<float4*>(&ha[n][k4 * 4]) = va;
            ushort4 h4b = *reinterpret_cast<const ushort4*>(hhi + ra + H);
            ushort4 l4b = *reinterpret_cast<const ushort4*>(hlo + ra + H);
            float4 vb;
            vb.x = bf2f(h4b.x) + bf2f(l4b.x);
            vb.y = bf2f(h4b.y) + bf2f(l4b.y);
            vb.z = bf2f(h4b.z) + bf2f(l4b.z);
            vb.w = bf2f(h4b.w) + bf2f(l4b.w);
            *reinterpret_cast<float4*>(&hb[n][k4 * 4]) = vb;
        }
    }
    __syncthreads();

    const int j = tid;
    float ai[NP], ao[NP], au[NP], axf[NP], afa[NP], afb[NP];
    {
        const float bi = b_iou[j];
        const float bo = b_iou[H + j];
        const float bu = b_iou[2 * H + j];
        const float bff = LEAF ? 0.0f : b_f[j];
        #pragma unroll
        for (int n = 0; n < NP; ++n) {
            ai[n] = bi; ao[n] = bo; au[n] = bu;
            axf[n] = bff; afa[n] = 0.0f; afb[n] = 0.0f;
        }
    }

    const float* pkj = g_pack + (size_t)j * 8;

    for (int kk = 0; kk < EMBD / 4; ++kk) {
        float4 wa[4], wb[4];
        #pragma unroll
        for (int r = 0; r < 4; ++r) {
            const float* p = pkj + (size_t)(kk * 4 + r) * 1024;
            wa[r] = *reinterpret_cast<const float4*>(p);
            if (!LEAF) wb[r] = *reinterpret_cast<const float4*>(p + 4);
        }
        #pragma unroll
        for (int n = 0; n < NP; ++n) {
            const float4 xv = *reinterpret_cast<const float4*>(&xe[n][kk * 4]);
            const float xs[4] = {xv.x, xv.y, xv.z, xv.w};
            if (!LEAF) {
                const float4 av = *reinterpret_cast<const float4*>(&ha[n][kk * 4]);
                const float4 bv = *reinterpret_cast<const float4*>(&hb[n][kk * 4]);
                const float as[4] = {av.x, av.y, av.z, av.w};
                const float bs[4] = {bv.x, bv.y, bv.z, bv.w};
                #pragma unroll
                for (int r = 0; r < 4; ++r) {
                    const float hs = as[r] + bs[r];
                    ai[n]  = fmaf(xs[r], wa[r].x, ai[n]);
                    ao[n]  = fmaf(xs[r], wa[r].y, ao[n]);
                    au[n]  = fmaf(xs[r], wa[r].z, au[n]);
                    ai[n]  = fmaf(hs,    wb[r].x, ai[n]);
                    ao[n]  = fmaf(hs,    wb[r].y, ao[n]);
                    au[n]  = fmaf(hs,    wb[r].z, au[n]);
                    axf[n] = fmaf(xs[r], wa[r].w, axf[n]);
                    afa[n] = fmaf(as[r], wb[r].w, afa[n]);
                    afb[n] = fmaf(bs[r], wb[r].w, afb[n]);
                }
            } else {
                #pragma unroll
                for (int r = 0; r < 4; ++r) {
                    ai[n] = fmaf(xs[r], wa[r].x, ai[n]);
                    ao[n] = fmaf(xs[r], wa[r].y, ao[n]);
                    au[n] = fmaf(xs[r], wa[r].z, au[n]);
                }
            }
        }
    }

    #pragma unroll
    for (int n = 0; n < NP; ++n) {
        if (n >= nval) break;
        const int node = nbase + n;
        const float iv = fast_sig(ai[n]);
        const float ov = fast_sig(ao[n]);
        const float uv = fast_tanh(au[n]);
        float cn;
        if (LEAF) {
            cn = iv * uv;
        } else {
            const float fav = fast_sig(axf[n] + afa[n]);
            const float fbv = fast_sig(axf[n] + afb[n]);
            const int a = 2 * node - seg.N - 1;
            const float ca  = cbuf[(size_t)(seg.hcOff + a) * H + j];
            const float cb2 = cbuf[(size_t)(seg.hcOff + a + 1) * H + j];
            cn = fmaf(fav, ca, fmaf(fbv, cb2, iv * uv));
        }
        const float hn = ov * fast_tanh(cn);
        const size_t o = (size_t)(seg.hcOff + node) * H + j;
        cbuf[o] = cn;
        const unsigned short hi16 = f2bf(hn);
        whhi[o] = hi16;
        whlo[o] = f2bf(hn - bf2f(hi16));
    }
}

// fuse_a_b @ h_c == h_a * dot(h_b, h_c); then 2-layer MLP with ReLU.
__global__ __launch_bounds__(128)
void final_kernel(const unsigned short* __restrict__ hhi, const unsigned short* __restrict__ hlo,
                  const float* __restrict__ fc1_w, const float* __restrict__ fc1_b,
                  const float* __restrict__ fc2_w, const float* __restrict__ fc2_b,
                  float* __restrict__ out,
                  int rc, int ra, int rb)
{
    __shared__ float sh[128];
    __shared__ float z1[64];
    __shared__ float dots[2];
    const int tid = threadIdx.x;

    const float hc  = bf2f(hhi[(size_t)rc * H + tid]) + bf2f(hlo[(size_t)rc * H + tid]);
    const float hav = bf2f(hhi[(size_t)ra * H + tid]) + bf2f(hlo[(size_t)ra * H + tid]);
    const float hbv = bf2f(hhi[(size_t)rb * H + tid]) + bf2f(hlo[(size_t)rb * H + tid]);

    float p = hbv * hc;
    #pragma unroll
    for (int o = 32; o > 0; o >>= 1) p += __shfl_down(p, o);
    if ((tid & 63) == 0) dots[tid >> 6] = p;
    __syncthreads();
    const float dot = dots[0] + dots[1];
    sh[tid] = hav * dot;
    __syncthreads();

    if (tid < 64) {
        float z = fc1_b[tid];
        for (int i = 0; i < 128; ++i) z = fmaf(sh[i], fc1_w[i * 64 + tid], z);
        z1[tid] = fmaxf(z, 0.0f);
    }
    __syncthreads();
    if (tid < 3) {
        float z = fc2_b[tid];
        for (int jj = 0; jj < 64; ++jj) z = fmaf(z1[jj], fc2_w[jj * 3 + tid], z);
        out[tid] = fmaxf(z, 0.0f);
    }
}

extern "C" void kernel_launch(void* const* d_in, const int* in_sizes, int n_in,
                              void* d_out, int out_size, void* d_ws, size_t ws_size,
                              hipStream_t stream) {
    const float* emb   = (const float*)d_in[12];
    const float* W_iou = (const float*)d_in[13];
    const float* b_iou = (const float*)d_in[14];
    const float* U_iou = (const float*)d_in[15];
    const float* W_f   = (const float*)d_in[16];
    const float* b_f   = (const float*)d_in[17];
    const float* U_f   = (const float*)d_in[18];
    const float* fc1_w = (const float*)d_in[19];
    const float* fc1_b = (const float*)d_in[20];
    const float* fc2_w = (const float*)d_in[21];
    const float* fc2_b = (const float*)d_in[22];
    const int* feats[3] = { (const int*)d_in[0], (const int*)d_in[4], (const int*)d_in[8] };

    const int D[3] = {17, 12, 12};
    const int N[3] = {131071, 4095, 4095};
    const int off[3] = {0, 131071, 131071 + 4095};

    float* cbuf = (float*)d_ws;
    unsigned short* hhi = (unsigned short*)(cbuf + (size_t)NTOT * 128);
    unsigned short* hlo = hhi + (size_t)NTOT * 128;

    pack_kernel<<<128, 128, 0, stream>>>(W_iou, W_f, U_iou, U_f);
    {
        const int NB3 = 384 * 1152 + 256 * 1152 + 384 * 384;
        pack_B<<<(NB3 + 255) / 256, 256, 0, stream>>>(W_iou, U_iou, W_f, U_f);
    }
    pack_emb<<<(VOCAB * 32 + 255) / 256, 256, 0, stream>>>(emb);

    auto mkseg = [&](int l, int t) {
        TreeSeg s;
        if (l <= D[t] - 1) {
            s.cnt   = 1 << (D[t] - 1 - l);
            s.start = N[t] - (1 << (D[t] - l)) + 1;
        } else { s.cnt = 0; s.start = 0; }
        s.hcOff = off[t]; s.N = N[t];
        return s;
    };

    // ---- leaf level (l=0): MFMA IOU-leaf ----
    {
        TreeSeg s0 = mkseg(0, 0), s1 = mkseg(0, 1), s2 = mkseg(0, 2);
        int b0 = (s0.cnt + 63) / 64, b1 = (s1.cnt + 63) / 64, b2 = (s2.cnt + 63) / 64;
        gemm_level<3, 2><<<b0 + b1 + b2, 512, 0, stream>>>(
            feats[0], feats[1], feats[2], hhi, hlo, hhi, hlo, cbuf,
            b_iou, b_f, s0, s1, s2, b0, b0 + b1);
    }

    // ---- levels 1..11: MFMA F then IOU (masked 64-row blocks) ----
    for (int l = 1; l <= 11; ++l) {
        TreeSeg s0 = mkseg(l, 0), s1 = mkseg(l, 1), s2 = mkseg(l, 2);
        int b0 = (s0.cnt + 63) / 64, b1 = (s1.cnt + 63) / 64, b2 = (s2.cnt + 63) / 64;
        const int total = b0 + b1 + b2;
        gemm_level<2, 0><<<total, 512, 0, stream>>>(
            feats[0], feats[1], feats[2], hhi, hlo, hhi, hlo, cbuf,
            b_iou, b_f, s0, s1, s2, b0, b0 + b1);
        gemm_level<3, 1><<<total, 512, 0, stream>>>(
            feats[0], feats[1], feats[2], hhi, hlo, hhi, hlo, cbuf,
            b_iou, b_f, s0, s1, s2, b0, b0 + b1);
    }

    // ---- levels 12..16: fp32 path (tiny, cube only) ----
    for (int l = 12; l < 17; ++l) {
        TreeSeg s[3];
        int total_parents = 0;
        for (int t = 0; t < 3; ++t) { s[t] = mkseg(l, t); total_parents += s[t].cnt; }
        if (total_parents == 0) continue;
        int blocks[3];
        for (int t = 0; t < 3; ++t) blocks[t] = (s[t].cnt + 1) / 2;
        const int total = blocks[0] + blocks[1] + blocks[2];
        level_kernel<2, false><<<total, BLOCK, 0, stream>>>(
            emb, b_iou, b_f, feats[0], feats[1], feats[2],
            hhi, hlo, hhi, hlo, cbuf,
            s[0], s[1], s[2], blocks[0], blocks[0] + blocks[1]);
    }

    const int rc = off[0] + N[0] - 1;
    const int ra = off[1] + N[1] - 1;
    const int rb = off[2] + N[2] - 1;
    final_kernel<<<1, 128, 0, stream>>>(hhi, hlo, fc1_w, fc1_b, fc2_w, fc2_b,
                                        (float*)d_out, rc, ra, rb);
}

// Round 13
// 489.034 us; speedup vs baseline: 1.3829x; 1.3829x over previous
//
#include <hip/hip_runtime.h>
#include <hip/hip_bf16.h>
#include <math.h>

#define H 128
#define EMBD 128
#define VOCAB 50000

typedef __attribute__((ext_vector_type(8))) short bf16x8;
typedef __attribute__((ext_vector_type(4))) float f32x4;

constexpr int BLOCK = 128;   // fp32 path: one thread per hidden dim
constexpr int NTOT = 131071 + 4095 + 4095;   // 139261

// fp32-path packed weights: g_pack[k][j][8]
__device__ float g_pack[128 * 128 * 8];
// MFMA packed weights, transposed [col][k'], k' bands = [hi(384) | hi-dup(384) | lo(384)]
__device__ unsigned short g_Biou[384 * 1152];
__device__ unsigned short g_Bf[256 * 1152];
__device__ unsigned short g_Bleaf[384 * 384];
// emb pre-split to bf16: row f = [hi(128) | lo(128)]
__device__ unsigned short g_embhl[VOCAB * 256];

// ---- shared-B schedule tables [MODE][bkt] ----
constexpr int SB_NBT[3] = {12, 8, 4};
constexpr int SB_KOFF[3][12] = {
    {0, 64, 128, 192, 256, 320, 768, 832, 896, 960, 1024, 1088},  // F
    {0, 64, 128, 192, 768, 832, 896, 960},                        // IOU
    {0, 64, 256, 320}                                             // leaf
};
constexpr int SB_NPL[3][12] = {
    {2, 2, 2, 2, 2, 2, 1, 1, 1, 1, 1, 1},
    {2, 2, 4, 4, 1, 1, 2, 2},
    {2, 2, 1, 1}
};
constexpr int SB_SEL[3][12][4] = {
    {{0,0},{0,0},{1,2},{1,2},{1,2},{1,2},{0},{0},{1},{1},{1},{1}},
    {{0,0},{0,0},{1,1,2,2},{1,1,2,2},{0},{0},{1,1},{1,1}},
    {{0,0},{0,0},{0},{0}}
};
constexpr int SB_OFF[3][12][4] = {
    {{0,128},{64,192},{0,0},{64,64},{128,128},{192,192},{0},{64},{0},{64},{128},{192}},
    {{0,128},{64,192},{0,128,0,128},{64,192,64,192},{0},{64},{0,128},{64,192}},
    {{0,128},{64,192},{0},{64}}
};

struct TreeSeg { int start, cnt, hcOff, N; };

__device__ __forceinline__ float fast_sig(float x)  { return 1.0f / (1.0f + __expf(-x)); }
__device__ __forceinline__ float fast_tanh(float x) { return 1.0f - 2.0f / (__expf(2.0f * x) + 1.0f); }
__device__ __forceinline__ unsigned short f2bf(float f) {
    unsigned int u = __float_as_uint(f);
    return (unsigned short)((u + 0x7FFFu + ((u >> 16) & 1u)) >> 16);
}
__device__ __forceinline__ float bf2f(unsigned short h) {
    return __uint_as_float(((unsigned int)h) << 16);
}
__device__ __forceinline__ unsigned short bf_split(float v, bool lo) {
    unsigned short hi = f2bf(v);
    return lo ? f2bf(v - bf2f(hi)) : hi;
}

// ---------------- single fused pack kernel (r11 pack math, flat ranges) ----------------
__global__ __launch_bounds__(256)
void pack_all(const float* __restrict__ Wiou, const float* __restrict__ Uiou,
              const float* __restrict__ Wf, const float* __restrict__ Uf,
              const float* __restrict__ emb)
{
    const int R0 = 128 * 128;              // g_pack items (k,j)
    const int R1 = R0 + 384 * 1152;        // g_Biou
    const int R2 = R1 + 256 * 1152;        // g_Bf
    const int R3 = R2 + 384 * 384;         // g_Bleaf
    const int R4 = R3 + VOCAB * 32;        // emb float4-groups
    int idx = blockIdx.x * 256 + threadIdx.x;
    if (idx < R0) {
        const int k = idx >> 7, j = idx & 127;
        float4 a, b;
        a.x = Wiou[k * 384 + j];
        a.y = Wiou[k * 384 + 128 + j];
        a.z = Wiou[k * 384 + 256 + j];
        a.w = Wf[k * 128 + j];
        b.x = Uiou[k * 384 + j];
        b.y = Uiou[k * 384 + 128 + j];
        b.z = Uiou[k * 384 + 256 + j];
        b.w = Uf[k * 128 + j];
        float4* o = reinterpret_cast<float4*>(g_pack + ((size_t)k * 128 + j) * 8);
        o[0] = a;
        o[1] = b;
    } else if (idx < R1) {
        int r = idx - R0;
        int c = r / 1152, k = r % 1152;
        int kb = k % 384; bool lo = k >= 768;
        float v = (kb < 128) ? Wiou[kb * 384 + c] : Uiou[((kb - 128) & 127) * 384 + c];
        g_Biou[c * 1152 + k] = bf_split(v, lo);
    } else if (idx < R2) {
        int r = idx - R1;
        int c = r / 1152, k = r % 1152;
        int kb = k % 384; bool lo = k >= 768;
        int g = c >> 7, j = c & 127;
        float v;
        if (kb < 128)      v = Wf[kb * 128 + j];
        else if (kb < 256) v = (g == 0) ? Uf[(kb - 128) * 128 + j] : 0.0f;
        else               v = (g == 1) ? Uf[(kb - 256) * 128 + j] : 0.0f;
        g_Bf[c * 1152 + k] = bf_split(v, lo);
    } else if (idx < R3) {
        int r = idx - R2;
        int c = r / 384, k = r % 384;
        int kb = k % 128; bool lo = k >= 256;
        g_Bleaf[c * 384 + k] = bf_split(Wiou[kb * 384 + c], lo);
    } else if (idx < R4) {
        int r = idx - R3;
        const int f = r >> 5, k4 = r & 31;
        float4 v = reinterpret_cast<const float4*>(emb + (size_t)f * 128)[k4];
        const float fv[4] = {v.x, v.y, v.z, v.w};
        ushort4 hi4, lo4;
        unsigned short* hp = reinterpret_cast<unsigned short*>(&hi4);
        unsigned short* lp = reinterpret_cast<unsigned short*>(&lo4);
        #pragma unroll
        for (int t = 0; t < 4; ++t) {
            unsigned short hb = f2bf(fv[t]);
            hp[t] = hb;
            lp[t] = f2bf(fv[t] - bf2f(hb));
        }
        *reinterpret_cast<ushort4*>(g_embhl + (size_t)f * 256 + k4 * 4) = hi4;
        *reinterpret_cast<ushort4*>(g_embhl + (size_t)f * 256 + 128 + k4 * 4) = lo4;
    }
}

// ---------------- MFMA level GEMM, 64-row tiles, shared-B staging (r11 verbatim) --------
// MODE 0 = F (NCH=2), 1 = IOU (NCH=3), 2 = IOU leaf (NCH=3, K'=384)
template<int NCH, int MODE>
__global__ __launch_bounds__(512, 2)
void gemm_level(const int* __restrict__ feat0, const int* __restrict__ feat1,
                const int* __restrict__ feat2,
                const unsigned short* __restrict__ hhi, const unsigned short* __restrict__ hlo,
                unsigned short* __restrict__ whhi, unsigned short* __restrict__ whlo,
                float* __restrict__ cbuf,
                const float* __restrict__ b_iou, const float* __restrict__ b_f,
                TreeSeg s0, TreeSeg s1, TreeSeg s2, int blocks0, int blocks01)
{
    constexpr int KP   = (MODE == 2) ? 384 : 1152;
    constexpr int NBT  = SB_NBT[MODE];
    constexpr int MAXP = (MODE == 1) ? 4 : 2;
    constexpr int NB   = NCH * 2;
    __shared__ unsigned short Als[MAXP][64 * 64];
    __shared__ unsigned short Bls[NCH * 128 * 64];

    const int bid = blockIdx.x;
    TreeSeg seg; const int* feat; int batch;
    if (bid < blocks0)       { seg = s0; feat = feat0; batch = bid; }
    else if (bid < blocks01) { seg = s1; feat = feat1; batch = bid - blocks0; }
    else                     { seg = s2; feat = feat2; batch = bid - blocks01; }

    const int tid = threadIdx.x;
    const int nbase = seg.start + batch * 64;

    // A staging: thread -> (row, slot)
    const int arow = tid >> 3, aslot = tid & 7;
    const int agnode = nbase + arow;
    const unsigned short* erow = g_embhl + (size_t)feat[agnode] * 256 + aslot * 8;
    const unsigned short* hrhi = erow;
    const unsigned short* hrlo = erow;
    if (MODE != 2) {
        const size_t hbase = (size_t)(seg.hcOff + 2 * agnode - seg.N - 1) * 128 + aslot * 8;
        hrhi = hhi + hbase;
        hrlo = hlo + hbase;
    }
    const int adst = arow * 64 + ((aslot ^ (arow & 7)) << 3);

    // B staging: single base + constexpr chunk offsets (low VGPR)
    const unsigned short* BT = (MODE == 0) ? g_Bf : ((MODE == 2) ? g_Bleaf : g_Biou);
    const int col0 = tid >> 3, slot = tid & 7;
    const unsigned short* bbase = BT + (size_t)col0 * KP + slot * 8;
    const int bd0 = col0 * 64 + ((slot ^ (col0 & 7)) << 3);

    auto srcPlane = [&](int bkt, int p) -> const unsigned short* {
        const int s = SB_SEL[MODE][bkt][p];
        const unsigned short* base = (s == 0) ? erow : ((s == 1) ? hrhi : hrlo);
        return base + SB_OFF[MODE][bkt][p];
    };

    f32x4 acc[2][NCH][2];
    #pragma unroll
    for (int a = 0; a < 2; ++a)
        #pragma unroll
        for (int b = 0; b < NCH; ++b)
            #pragma unroll
            for (int d = 0; d < 2; ++d) acc[a][b][d] = (f32x4){0.f, 0.f, 0.f, 0.f};

    const int lane = tid & 63;
    const int wv = tid >> 6;
    const int wm = wv >> 2, wn = wv & 3;
    const int l15 = lane & 15, l4 = lane >> 4;

    auto mfma_phase = [&](int at) {
        #pragma unroll
        for (int st = 0; st < 2; ++st) {
            const int q = st * 4 + l4;
            bf16x8 af[2];
            #pragma unroll
            for (int fm = 0; fm < 2; ++fm) {
                const int row = wm * 32 + fm * 16 + l15;
                af[fm] = *reinterpret_cast<const bf16x8*>(&Als[at][row * 64 + ((q ^ (row & 7)) << 3)]);
            }
            #pragma unroll
            for (int ch = 0; ch < NCH; ++ch) {
                #pragma unroll
                for (int fc = 0; fc < 2; ++fc) {
                    const int col = ch * 128 + wn * 32 + fc * 16 + l15;
                    const bf16x8 bfr = *reinterpret_cast<const bf16x8*>(&Bls[col * 64 + ((q ^ (col & 7)) << 3)]);
                    #pragma unroll
                    for (int fm = 0; fm < 2; ++fm)
                        acc[fm][ch][fc] = __builtin_amdgcn_mfma_f32_16x16x32_bf16(af[fm], bfr, acc[fm][ch][fc], 0, 0, 0);
                }
            }
        }
    };

    // prologue: prefetch bkt 0
    bf16x8 aR[MAXP], bR[NB];
    #pragma unroll
    for (int it = 0; it < NB; ++it)
        bR[it] = *reinterpret_cast<const bf16x8*>(bbase + (size_t)it * 64 * KP + SB_KOFF[MODE][0]);
    #pragma unroll
    for (int p = 0; p < MAXP; ++p)
        if (p < SB_NPL[MODE][0]) aR[p] = *reinterpret_cast<const bf16x8*>(srcPlane(0, p));

    #pragma unroll
    for (int bkt = 0; bkt < NBT; ++bkt) {
        #pragma unroll
        for (int it = 0; it < NB; ++it)
            *reinterpret_cast<bf16x8*>(&Bls[bd0 + it * 64 * 64]) = bR[it];
        #pragma unroll
        for (int p = 0; p < MAXP; ++p)
            if (p < SB_NPL[MODE][bkt]) *reinterpret_cast<bf16x8*>(&Als[p][adst]) = aR[p];
        if (bkt + 1 < NBT) {
            #pragma unroll
            for (int it = 0; it < NB; ++it)
                bR[it] = *reinterpret_cast<const bf16x8*>(bbase + (size_t)it * 64 * KP + SB_KOFF[MODE][bkt + 1]);
            #pragma unroll
            for (int p = 0; p < MAXP; ++p)
                if (p < SB_NPL[MODE][bkt + 1]) aR[p] = *reinterpret_cast<const bf16x8*>(srcPlane(bkt + 1, p));
        }
        __syncthreads();
        #pragma unroll
        for (int p = 0; p < MAXP; ++p)
            if (p < SB_NPL[MODE][bkt]) mfma_phase(p);
        __syncthreads();
    }

    // ---- fused epilogue ----
    #pragma unroll
    for (int fc = 0; fc < 2; ++fc) {
        const int j = wn * 32 + fc * 16 + l15;
        float bi = 0.f, bo = 0.f, bu = 0.f, bff = 0.f;
        if (MODE == 0) { bff = b_f[j]; }
        else { bi = b_iou[j]; bo = b_iou[128 + j]; bu = b_iou[256 + j]; }
        #pragma unroll
        for (int fm = 0; fm < 2; ++fm) {
            #pragma unroll
            for (int r = 0; r < 4; ++r) {
                const int row_local = wm * 32 + fm * 16 + l4 * 4 + r;
                const int gnode = nbase + row_local;
                const size_t crow = (size_t)(seg.hcOff + gnode) * 128;
                if constexpr (MODE == 0) {
                    const size_t cbase = (size_t)(seg.hcOff + 2 * gnode - seg.N - 1) * 128;
                    const float fa = fast_sig(acc[fm][0][fc][r] + bff);
                    const float fb = fast_sig(acc[fm][1][fc][r] + bff);
                    cbuf[crow + j] = fa * cbuf[cbase + j] + fb * cbuf[cbase + 128 + j];
                } else {
                    const float iv = fast_sig(acc[fm][0][fc][r] + bi);
                    const float ov = fast_sig(acc[fm][1][fc][r] + bo);
                    const float uv = fast_tanh(acc[fm][NCH - 1][fc][r] + bu);
                    float cn = iv * uv;
                    if (MODE == 1) cn += cbuf[crow + j];
                    cbuf[crow + j] = cn;
                    const float hn = ov * fast_tanh(cn);
                    const unsigned short hi16 = f2bf(hn);
                    whhi[crow + j] = hi16;
                    whlo[crow + j] = f2bf(hn - bf2f(hi16));
                }
            }
        }
    }
}

// ---------------- fp32 path for levels 4..16 (r11 verbatim) ----------------
template<int NP, bool LEAF>
__global__ __launch_bounds__(BLOCK, 2)
void level_kernel(const float* __restrict__ emb,
                  const float* __restrict__ b_iou, const float* __restrict__ b_f,
                  const int* __restrict__ feat0, const int* __restrict__ feat1,
                  const int* __restrict__ feat2,
                  const unsigned short* __restrict__ hhi, const unsigned short* __restrict__ hlo,
                  unsigned short* __restrict__ whhi, unsigned short* __restrict__ whlo,
                  float* __restrict__ cbuf,
                  TreeSeg s0, TreeSeg s1, TreeSeg s2,
                  int blocks0, int blocks01)
{
    __shared__ float xe[NP][EMBD];
    __shared__ float ha[LEAF ? 1 : NP][EMBD];
    __shared__ float hb[LEAF ? 1 : NP][EMBD];

    const int bid = blockIdx.x;
    TreeSeg seg; const int* feat; int batch;
    if (bid < blocks0)       { seg = s0; feat = feat0; batch = bid; }
    else if (bid < blocks01) { seg = s1; feat = feat1; batch = bid - blocks0; }
    else                     { seg = s2; feat = feat2; batch = bid - blocks01; }

    const int tid = threadIdx.x;
    const int nbase = seg.start + batch * NP;
    const int nval  = min(NP, seg.start + seg.cnt - nbase);

    for (int idx = tid; idx < NP * (EMBD / 4); idx += BLOCK) {
        const int n  = idx >> 5;
        const int k4 = idx & 31;
        const int node = nbase + min(n, nval - 1);
        const int f = feat[node];
        float4 v = reinterpret_cast<const float4*>(emb + (size_t)f * EMBD)[k4];
        *reinterpret_cast<float4*>(&xe[n][k4 * 4]) = v;
        if (!LEAF) {
            const int a = 2 * node - seg.N - 1;
            const size_t ra = (size_t)(seg.hcOff + a) * H + k4 * 4;
            ushort4 h4 = *reinterpret_cast<const ushort4*>(hhi + ra);
            ushort4 l4v = *reinterpret_cast<const ushort4*>(hlo + ra);
            float4 va;
            va.x = bf2f(h4.x) + bf2f(l4v.x);
            va.y = bf2f(h4.y) + bf2f(l4v.y);
            va.z = bf2f(h4.z) + bf2f(l4v.z);
            va.w = bf2f(h4.w) + bf2f(l4v.w);
            *reinterpret_cast<float4*>(&ha[n][k4 * 4]) = va;
            ushort4 h4b = *reinterpret_cast<const ushort4*>(hhi + ra + H);
            ushort4 l4b = *reinterpret_cast<const ushort4*>(hlo + ra + H);
            float4 vb;
            vb.x = bf2f(h4b.x) + bf2f(l4b.x);
            vb.y = bf2f(h4b.y) + bf2f(l4b.y);
            vb.z = bf2f(h4b.z) + bf2f(l4b.z);
            vb.w = bf2f(h4b.w) + bf2f(l4b.w);
            *reinterpret_cast<float4*>(&hb[n][k4 * 4]) = vb;
        }
    }
    __syncthreads();

    const int j = tid;
    float ai[NP], ao[NP], au[NP], axf[NP], afa[NP], afb[NP];
    {
        const float bi = b_iou[j];
        const float bo = b_iou[H + j];
        const float bu = b_iou[2 * H + j];
        const float bff = LEAF ? 0.0f : b_f[j];
        #pragma unroll
        for (int n = 0; n < NP; ++n) {
            ai[n] = bi; ao[n] = bo; au[n] = bu;
            axf[n] = bff; afa[n] = 0.0f; afb[n] = 0.0f;
        }
    }

    const float* pkj = g_pack + (size_t)j * 8;

    for (int kk = 0; kk < EMBD / 4; ++kk) {
        float4 wa[4], wb[4];
        #pragma unroll
        for (int r = 0; r < 4; ++r) {
            const float* p = pkj + (size_t)(kk * 4 + r) * 1024;
            wa[r] = *reinterpret_cast<const float4*>(p);
            if (!LEAF) wb[r] = *reinterpret_cast<const float4*>(p + 4);
        }
        #pragma unroll
        for (int n = 0; n < NP; ++n) {
            const float4 xv = *reinterpret_cast<const float4*>(&xe[n][kk * 4]);
            const float xs[4] = {xv.x, xv.y, xv.z, xv.w};
            if (!LEAF) {
                const float4 av = *reinterpret_cast<const float4*>(&ha[n][kk * 4]);
                const float4 bv = *reinterpret_cast<const float4*>(&hb[n][kk * 4]);
                const float as[4] = {av.x, av.y, av.z, av.w};
                const float bs[4] = {bv.x, bv.y, bv.z, bv.w};
                #pragma unroll
                for (int r = 0; r < 4; ++r) {
                    const float hs = as[r] + bs[r];
                    ai[n]  = fmaf(xs[r], wa[r].x, ai[n]);
                    ao[n]  = fmaf(xs[r], wa[r].y, ao[n]);
                    au[n]  = fmaf(xs[r], wa[r].z, au[n]);
                    ai[n]  = fmaf(hs,    wb[r].x, ai[n]);
                    ao[n]  = fmaf(hs,    wb[r].y, ao[n]);
                    au[n]  = fmaf(hs,    wb[r].z, au[n]);
                    axf[n] = fmaf(xs[r], wa[r].w, axf[n]);
                    afa[n] = fmaf(as[r], wb[r].w, afa[n]);
                    afb[n] = fmaf(bs[r], wb[r].w, afb[n]);
                }
            } else {
                #pragma unroll
                for (int r = 0; r < 4; ++r) {
                    ai[n] = fmaf(xs[r], wa[r].x, ai[n]);
                    ao[n] = fmaf(xs[r], wa[r].y, ao[n]);
                    au[n] = fmaf(xs[r], wa[r].z, au[n]);
                }
            }
        }
    }

    #pragma unroll
    for (int n = 0; n < NP; ++n) {
        if (n >= nval) break;
        const int node = nbase + n;
        const float iv = fast_sig(ai[n]);
        const float ov = fast_sig(ao[n]);
        const float uv = fast_tanh(au[n]);
        float cn;
        if (LEAF) {
            cn = iv * uv;
        } else {
            const float fav = fast_sig(axf[n] + afa[n]);
            const float fbv = fast_sig(axf[n] + afb[n]);
            const int a = 2 * node - seg.N - 1;
            const float ca  = cbuf[(size_t)(seg.hcOff + a) * H + j];
            const float cb2 = cbuf[(size_t)(seg.hcOff + a + 1) * H + j];
            cn = fmaf(fav, ca, fmaf(fbv, cb2, iv * uv));
        }
        const float hn = ov * fast_tanh(cn);
        const size_t o = (size_t)(seg.hcOff + node) * H + j;
        cbuf[o] = cn;
        const unsigned short hi16 = f2bf(hn);
        whhi[o] = hi16;
        whlo[o] = f2bf(hn - bf2f(hi16));
    }
}

// fuse_a_b @ h_c == h_a * dot(h_b, h_c); then 2-layer MLP with ReLU.
__global__ __launch_bounds__(128)
void final_kernel(const unsigned short* __restrict__ hhi, const unsigned short* __restrict__ hlo,
                  const float* __restrict__ fc1_w, const float* __restrict__ fc1_b,
                  const float* __restrict__ fc2_w, const float* __restrict__ fc2_b,
                  float* __restrict__ out,
                  int rc, int ra, int rb)
{
    __shared__ float sh[128];
    __shared__ float z1[64];
    __shared__ float dots[2];
    const int tid = threadIdx.x;

    const float hc  = bf2f(hhi[(size_t)rc * H + tid]) + bf2f(hlo[(size_t)rc * H + tid]);
    const float hav = bf2f(hhi[(size_t)ra * H + tid]) + bf2f(hlo[(size_t)ra * H + tid]);
    const float hbv = bf2f(hhi[(size_t)rb * H + tid]) + bf2f(hlo[(size_t)rb * H + tid]);

    float p = hbv * hc;
    #pragma unroll
    for (int o = 32; o > 0; o >>= 1) p += __shfl_down(p, o);
    if ((tid & 63) == 0) dots[tid >> 6] = p;
    __syncthreads();
    const float dot = dots[0] + dots[1];
    sh[tid] = hav * dot;
    __syncthreads();

    if (tid < 64) {
        float z = fc1_b[tid];
        for (int i = 0; i < 128; ++i) z = fmaf(sh[i], fc1_w[i * 64 + tid], z);
        z1[tid] = fmaxf(z, 0.0f);
    }
    __syncthreads();
    if (tid < 3) {
        float z = fc2_b[tid];
        for (int jj = 0; jj < 64; ++jj) z = fmaf(z1[jj], fc2_w[jj * 3 + tid], z);
        out[tid] = fmaxf(z, 0.0f);
    }
}

extern "C" void kernel_launch(void* const* d_in, const int* in_sizes, int n_in,
                              void* d_out, int out_size, void* d_ws, size_t ws_size,
                              hipStream_t stream) {
    const float* emb   = (const float*)d_in[12];
    const float* W_iou = (const float*)d_in[13];
    const float* b_iou = (const float*)d_in[14];
    const float* U_iou = (const float*)d_in[15];
    const float* W_f   = (const float*)d_in[16];
    const float* b_f   = (const float*)d_in[17];
    const float* U_f   = (const float*)d_in[18];
    const float* fc1_w = (const float*)d_in[19];
    const float* fc1_b = (const float*)d_in[20];
    const float* fc2_w = (const float*)d_in[21];
    const float* fc2_b = (const float*)d_in[22];
    const int* feats[3] = { (const int*)d_in[0], (const int*)d_in[4], (const int*)d_in[8] };

    const int D[3] = {17, 12, 12};
    const int N[3] = {131071, 4095, 4095};
    const int off[3] = {0, 131071, 131071 + 4095};

    float* cbuf = (float*)d_ws;
    unsigned short* hhi = (unsigned short*)(cbuf + (size_t)NTOT * 128);
    unsigned short* hlo = hhi + (size_t)NTOT * 128;

    {
        const int total = 128 * 128 + 384 * 1152 + 256 * 1152 + 384 * 384 + VOCAB * 32;
        pack_all<<<(total + 255) / 256, 256, 0, stream>>>(W_iou, U_iou, W_f, U_f, emb);
    }

    auto mkseg = [&](int l, int t) {
        TreeSeg s;
        if (l <= D[t] - 1) {
            s.cnt   = 1 << (D[t] - 1 - l);
            s.start = N[t] - (1 << (D[t] - l)) + 1;
        } else { s.cnt = 0; s.start = 0; }
        s.hcOff = off[t]; s.N = N[t];
        return s;
    };

    // ---- leaf level (l=0): MFMA IOU-leaf ----
    {
        TreeSeg s0 = mkseg(0, 0), s1 = mkseg(0, 1), s2 = mkseg(0, 2);
        int b0 = s0.cnt / 64, b1 = s1.cnt / 64, b2 = s2.cnt / 64;
        gemm_level<3, 2><<<b0 + b1 + b2, 512, 0, stream>>>(
            feats[0], feats[1], feats[2], hhi, hlo, hhi, hlo, cbuf,
            b_iou, b_f, s0, s1, s2, b0, b0 + b1);
    }

    // ---- levels 1..3: MFMA F then IOU ----
    for (int l = 1; l <= 3; ++l) {
        TreeSeg s0 = mkseg(l, 0), s1 = mkseg(l, 1), s2 = mkseg(l, 2);
        int b0 = s0.cnt / 64, b1 = s1.cnt / 64, b2 = s2.cnt / 64;
        const int total = b0 + b1 + b2;
        gemm_level<2, 0><<<total, 512, 0, stream>>>(
            feats[0], feats[1], feats[2], hhi, hlo, hhi, hlo, cbuf,
            b_iou, b_f, s0, s1, s2, b0, b0 + b1);
        gemm_level<3, 1><<<total, 512, 0, stream>>>(
            feats[0], feats[1], feats[2], hhi, hlo, hhi, hlo, cbuf,
            b_iou, b_f, s0, s1, s2, b0, b0 + b1);
    }

    // ---- levels 4..16: fp32 path, NP sized for wave occupancy ----
    // NP4 when parents >= 2048 (more blocks -> more resident waves -> latency hidden);
    // NP2 otherwise (small levels are per-block-serial bound regardless).
    for (int l = 4; l < 17; ++l) {
        TreeSeg s[3];
        int total_parents = 0;
        for (int t = 0; t < 3; ++t) { s[t] = mkseg(l, t); total_parents += s[t].cnt; }
        if (total_parents == 0) continue;
        const int NPsel = (total_parents >= 2048) ? 4 : 2;
        int blocks[3];
        for (int t = 0; t < 3; ++t) blocks[t] = (s[t].cnt + NPsel - 1) / NPsel;
        const int total = blocks[0] + blocks[1] + blocks[2];
        if (NPsel == 4) {
            level_kernel<4, false><<<total, BLOCK, 0, stream>>>(
                emb, b_iou, b_f, feats[0], feats[1], feats[2],
                hhi, hlo, hhi, hlo, cbuf,
                s[0], s[1], s[2], blocks[0], blocks[0] + blocks[1]);
        } else {
            level_kernel<2, false><<<total, BLOCK, 0, stream>>>(
                emb, b_iou, b_f, feats[0], feats[1], feats[2],
                hhi, hlo, hhi, hlo, cbuf,
                s[0], s[1], s[2], blocks[0], blocks[0] + blocks[1]);
        }
    }

    const int rc = off[0] + N[0] - 1;
    const int ra = off[1] + N[1] - 1;
    const int rb = off[2] + N[2] - 1;
    final_kernel<<<1, 128, 0, stream>>>(hhi, hlo, fc1_w, fc1_b, fc2_w, fc2_b,
                                        (float*)d_out, rc, ra, rb);
}